// Round 9
// baseline (60.174 us; speedup 1.0000x reference)
//
#include <hip/hip_runtime.h>
#include <hip/hip_bf16.h>

#define N_SAMPLES 4096
#define DIM 512
#define BM 128
#define BK 64
#define NK (DIM / BK)                 // 8 K-steps
#define NBT (N_SAMPLES / BM)          // 32 tiles per dim
#define NTILES (NBT * (NBT + 1) / 2)  // 528 upper-triangle tiles

typedef __attribute__((ext_vector_type(8))) short short8;
typedef __attribute__((ext_vector_type(4))) float floatx4;

__device__ __forceinline__ void gload_lds16(const void* gptr, void* lptr) {
    __builtin_amdgcn_global_load_lds(
        (const __attribute__((address_space(1))) void*)gptr,
        (__attribute__((address_space(3))) void*)lptr, 16, 0, 0);
}

__device__ __forceinline__ short bf16bits(float x) {
    __hip_bfloat16 h = __float2bfloat16(x);
    return *reinterpret_cast<short*>(&h);
}

// ---------------------------------------------------------------------------
// Kernel 1: row L2-normalize fp32 -> bf16 G. One wave per row, no barriers,
// float4 loads + short8 store (R8's fast version, measured cheap).
// Also zeroes row_sum/pos_sum and the done counter (replaces memset dispatch).
// ---------------------------------------------------------------------------
__global__ __launch_bounds__(512) void scl_normalize(
    const float* __restrict__ F, __hip_bfloat16* __restrict__ G,
    float* __restrict__ row_sum, float* __restrict__ pos_sum,
    unsigned int* __restrict__ done)
{
    const int t = threadIdx.x;
    const int lane = t & 63;
    const int row = blockIdx.x * 8 + (t >> 6);
    const float4* fr = (const float4*)(F + (size_t)row * DIM);
    float4 va = fr[lane * 2];
    float4 vb = fr[lane * 2 + 1];
    float ss = va.x * va.x + va.y * va.y + va.z * va.z + va.w * va.w +
               vb.x * vb.x + vb.y * vb.y + vb.z * vb.z + vb.w * vb.w;
    #pragma unroll
    for (int off = 1; off < 64; off <<= 1) ss += __shfl_xor(ss, off);
    float inv = ss > 0.f ? 1.0f / sqrtf(ss) : 0.f;
    short8 h;
    h[0] = bf16bits(va.x * inv); h[1] = bf16bits(va.y * inv);
    h[2] = bf16bits(va.z * inv); h[3] = bf16bits(va.w * inv);
    h[4] = bf16bits(vb.x * inv); h[5] = bf16bits(vb.y * inv);
    h[6] = bf16bits(vb.z * inv); h[7] = bf16bits(vb.w * inv);
    ((short8*)((short*)G + (size_t)row * DIM))[lane] = h;
    if (lane == 0) { row_sum[row] = 0.f; pos_sum[row] = 0.f; }
    if (t == 0 && blockIdx.x == 0) *done = 0u;
}

// ---------------------------------------------------------------------------
// Kernel 2: R2's exact GEMM core (best measured triangle config, from the
// 54.1 us best-total round): upper-triangle tile (bi<=bj) of S = G*G^T,
// bf16 MFMA 16x16x32, 256 threads = 4 waves (2x2) with 64x64 wave tiles,
// DOUBLE-buffered 64 KB LDS, prefetch issued before compute, XOR-swizzled
// LDS (linear gload_lds dest + XOR'd global source chunk + XOR'd ds_read;
// measured ~665 bank-conflict cycles), XCD-chunked block remap (bijective,
// 528 %% 8 == 0). Epilogue: exp + atomic row sums (+ atomic col sums
// off-diag; S symmetric so col sums are the mirrored tile's row sums).
// Fused last-block finalize (R6-verified pattern) saves a dispatch.
// ---------------------------------------------------------------------------
__global__ __launch_bounds__(256) void scl_gemm_epilogue(
    const __hip_bfloat16* __restrict__ G,
    const int* __restrict__ labels,
    float* __restrict__ row_sum,
    float* __restrict__ pos_sum,
    unsigned int* __restrict__ done,
    float* __restrict__ out)
{
    __shared__ __align__(16) short As[2][BM * BK];   // 2 x 16 KB
    __shared__ __align__(16) short Bs[2][BM * BK];   // 2 x 16 KB -> 64 KB

    const int t = threadIdx.x;
    const int lane = t & 63;
    const int q = lane >> 4;            // quarter-group 0..3 (k-chunk)
    const int wid = t >> 6;             // 0..3
    const int wr = wid >> 1;            // wave row 0..1 (64 rows)
    const int wc = wid & 1;             // wave col 0..1 (64 cols)

    // XCD-chunked swizzle (bijective: 528 % 8 == 0)
    int b = blockIdx.x;
    b = (b & 7) * (NTILES / 8) + (b >> 3);

    // triangular decode: b -> (bi <= bj)
    int bi = (int)((65.0f - sqrtf(4225.0f - 8.0f * (float)b)) * 0.5f);
    while (32 * bi - bi * (bi - 1) / 2 > b) --bi;
    while (32 * (bi + 1) - (bi + 1) * bi / 2 <= b) ++bi;
    const int bj = bi + (b - (32 * bi - bi * (bi - 1) / 2));
    const int brow = bi * BM;
    const int bcol = bj * BM;
    const bool isdiag = (bi == bj);

    const short* Gs = (const short*)G;

    floatx4 acc[4][4];
    #pragma unroll
    for (int m = 0; m < 4; m++)
        #pragma unroll
        for (int n = 0; n < 4; n++)
            acc[m][n] = (floatx4)0.f;

    // stage one K-tile; source chunk XOR'd so swizzled ds_read reads linear.
    auto stage = [&](int buf, int k0) {
        #pragma unroll
        for (int r = 0; r < 4; r++) {
            int idx = r * 256 + t;              // 16B chunk id, 0..1023
            int row = idx >> 3;                 // tile row 0..127
            int cg = (idx & 7) ^ (row & 7);     // swizzled k-chunk
            gload_lds16(Gs + (size_t)(brow + row) * DIM + k0 + cg * 8,
                        As[buf] + idx * 8);
            if (!isdiag)
                gload_lds16(Gs + (size_t)(bcol + row) * DIM + k0 + cg * 8,
                            Bs[buf] + idx * 8);
        }
    };

    stage(0, 0);
    __syncthreads();
    int cur = 0;
    for (int kt = 0; kt < NK; ++kt) {
        if (kt + 1 < NK) stage(cur ^ 1, (kt + 1) * BK);   // prefetch in flight
        const short* Ab = As[cur];
        const short* Bb = isdiag ? As[cur] : Bs[cur];
        #pragma unroll
        for (int kk = 0; kk < 2; kk++) {
            short8 a[4], bfr[4];
            #pragma unroll
            for (int m = 0; m < 4; m++) {
                int row = wr * 64 + m * 16 + (lane & 15);
                a[m] = *(const short8*)(Ab + row * BK +
                        (((kk * 4 + q) ^ (row & 7)) * 8));
            }
            #pragma unroll
            for (int n = 0; n < 4; n++) {
                int row = wc * 64 + n * 16 + (lane & 15);
                bfr[n] = *(const short8*)(Bb + row * BK +
                        (((kk * 4 + q) ^ (row & 7)) * 8));
            }
            #pragma unroll
            for (int m = 0; m < 4; m++)
                #pragma unroll
                for (int n = 0; n < 4; n++)
                    acc[m][n] = __builtin_amdgcn_mfma_f32_16x16x32_bf16(
                        a[m], bfr[n], acc[m][n], 0, 0, 0);
        }
        __syncthreads();   // drains prefetch vmcnt (had whole compute to fly)
        cur ^= 1;
    }

    // ---- epilogue ----
    // C/D layout: col = lane&15, row = q*4 + reg (m89-verified)
    const int colbase = bcol + wc * 64 + (lane & 15);
    int lc[4];
    #pragma unroll
    for (int n = 0; n < 4; n++) lc[n] = labels[colbase + n * 16];

    float pcr[4] = {0.f, 0.f, 0.f, 0.f};   // column partials (row_sum of S^T)
    float pcp[4] = {0.f, 0.f, 0.f, 0.f};

    #pragma unroll
    for (int m = 0; m < 4; m++) {
        #pragma unroll
        for (int j = 0; j < 4; j++) {
            const int i = brow + wr * 64 + m * 16 + q * 4 + j;
            const int li = labels[i];
            float pr = 0.f, pp = 0.f;
            #pragma unroll
            for (int n = 0; n < 4; n++) {
                float e = __expf(10.0f * acc[m][n][j]);
                bool dg = (i == colbase + n * 16);     // only on diag tiles
                bool pos = (li == lc[n]) && !dg;
                float er = dg ? 0.f : e;
                float ep = pos ? e : 0.f;
                pr += er;
                pp += ep;
                pcr[n] += er;
                pcp[n] += ep;
            }
            #pragma unroll
            for (int off = 1; off < 16; off <<= 1) {
                pr += __shfl_xor(pr, off);
                pp += __shfl_xor(pp, off);
            }
            if ((lane & 15) == 0) {
                atomicAdd(&row_sum[i], pr);
                atomicAdd(&pos_sum[i], pp);
            }
        }
    }

    if (!isdiag) {
        #pragma unroll
        for (int n = 0; n < 4; n++) {
            pcr[n] += __shfl_xor(pcr[n], 16);
            pcr[n] += __shfl_xor(pcr[n], 32);
            pcp[n] += __shfl_xor(pcp[n], 16);
            pcp[n] += __shfl_xor(pcp[n], 32);
        }
        if (lane < 16) {
            #pragma unroll
            for (int n = 0; n < 4; n++) {
                atomicAdd(&row_sum[colbase + n * 16], pcr[n]);
                atomicAdd(&pos_sum[colbase + n * 16], pcp[n]);
            }
        }
    }

    // ---- last-block-done fused finalize (LDS scratch aliases As/Bs) ----
    int* hist = (int*)&As[0][0];           // 16 ints
    int* slast = ((int*)&As[0][0]) + 16;   // 1 int
    double* red = (double*)&Bs[0][0];      // 12 doubles

    __syncthreads();
    if (t == 0) {
        __threadfence();                   // release: publish atomics
        unsigned int old = atomicAdd(done, 1u);
        *slast = (old == NTILES - 1) ? 1 : 0;
    }
    __syncthreads();
    if (!*slast) return;
    __threadfence();                       // acquire side

    if (t < 16) hist[t] = 0;
    __syncthreads();
    for (int i = t; i < N_SAMPLES; i += 256)
        atomicAdd(&hist[labels[i] & 15], 1);
    __syncthreads();

    double a = 0.0, bb = 0.0, c = 0.0;
    for (int i = t; i < N_SAMPLES; i += 256) {
        int cnt = hist[labels[i] & 15] - 1;
        float rs = __hip_atomic_load(&row_sum[i], __ATOMIC_RELAXED,
                                     __HIP_MEMORY_SCOPE_AGENT);
        float ps = __hip_atomic_load(&pos_sum[i], __ATOMIC_RELAXED,
                                     __HIP_MEMORY_SCOPE_AGENT);
        a -= (double)__logf(rs);
        double inv = 1.0 / (double)cnt;
        bb += inv;
        c += (double)__logf(ps + (float)(N_SAMPLES - cnt)) * inv;
    }
    #pragma unroll
    for (int off = 1; off < 64; off <<= 1) {
        a += __shfl_xor(a, off);
        bb += __shfl_xor(bb, off);
        c += __shfl_xor(c, off);
    }
    if (lane == 0) {
        red[wid] = a; red[4 + wid] = bb; red[8 + wid] = c;
    }
    __syncthreads();
    if (t == 0) {
        double A = 0, B = 0, C = 0;
        #pragma unroll
        for (int w = 0; w < 4; w++) { A += red[w]; B += red[4 + w]; C += red[8 + w]; }
        double res = -(A * B + (double)N_SAMPLES * C) /
                     ((double)N_SAMPLES * (double)N_SAMPLES);
        out[0] = (float)res;
    }
}

// ---------------------------------------------------------------------------
extern "C" void kernel_launch(void* const* d_in, const int* in_sizes, int n_in,
                              void* d_out, int out_size, void* d_ws, size_t ws_size,
                              hipStream_t stream)
{
    const float* F = (const float*)d_in[0];
    const int* labels = (const int*)d_in[1];
    float* out = (float*)d_out;

    char* ws = (char*)d_ws;
    __hip_bfloat16* G = (__hip_bfloat16*)ws;                        // 4 MB
    float* row_sum = (float*)(ws + (size_t)N_SAMPLES * DIM * 2);
    float* pos_sum = row_sum + N_SAMPLES;
    unsigned int* done = (unsigned int*)(pos_sum + N_SAMPLES);

    scl_normalize<<<N_SAMPLES / 8, 512, 0, stream>>>(F, G, row_sum, pos_sum, done);
    scl_gemm_epilogue<<<NTILES, 256, 0, stream>>>(G, labels, row_sum, pos_sum,
                                                  done, out);
}